// Round 1
// baseline (187.251 us; speedup 1.0000x reference)
//
#include <hip/hip_runtime.h>
#include <math.h>

// Discounted returns: ret[t] = r[t] + g*ret[t+1], then (ret - mean)/(std + eps).
// gamma^2048 ~ 1.1e-9 -> each block seeds its carry from a 2048-elem lookahead
// it reads itself. No inter-block dependency at all.

#define GAMMA 0.99f
#define EPSN  1e-4

constexpr int BLOCK  = 256;
constexpr int VPT    = 32;              // main elements per thread
constexpr int CHUNK  = BLOCK * VPT;     // 8192 per block
constexpr int VPT_LA = 8;               // lookahead elements per thread (2048 total)

__host__ __device__ constexpr float gpow(int k) {
  double p = 1.0;
  for (int i = 0; i < k; ++i) p *= 0.99;
  return (float)p;
}

__device__ __forceinline__ float4 load4g(const float* __restrict__ p, long long i, long long n) {
  if (i + 3 < n) return *reinterpret_cast<const float4*>(p + i);
  float4 v = make_float4(0.f, 0.f, 0.f, 0.f);   // beyond-end == semantic zero
  if (i < n)     v.x = p[i];
  if (i + 1 < n) v.y = p[i + 1];
  if (i + 2 < n) v.z = p[i + 2];
  return v;
}

__device__ __forceinline__ void store4g(float* __restrict__ p, long long i, long long n, float4 v) {
  if (i + 3 < n) { *reinterpret_cast<float4*>(p + i) = v; return; }
  if (i < n)     p[i] = v.x;
  if (i + 1 < n) p[i + 1] = v.y;
  if (i + 2 < n) p[i + 2] = v.z;
}

// Affine map f(x) = b + a*x per thread; suffix composition f_t o f_{t+1} o ... .
// combine(left,right) = (a_l*a_r, b_l + a_l*b_r).
__device__ __forceinline__ void wave_sufscan(float& a, float& b, int lane) {
#pragma unroll
  for (int d = 1; d < 64; d <<= 1) {
    float oa = __shfl_down(a, d);
    float ob = __shfl_down(b, d);
    if (lane + d < 64) { b = fmaf(a, ob, b); a *= oa; }
  }
}

// Exclusive suffix over the whole 256-thread block (threads > t).
__device__ __forceinline__ void block_sufscan_excl(float a, float b, float& ea, float& eb,
                                                   float* la_, float* lb_) {
  const int lane = threadIdx.x & 63;
  const int wv   = threadIdx.x >> 6;
  float ia = a, ib = b;
  wave_sufscan(ia, ib, lane);
  // exclusive within wave = inclusive of lane+1 (identity for lane 63)
  float xa = __shfl_down(ia, 1);
  float xb = __shfl_down(ib, 1);
  if (lane == 63) { xa = 1.f; xb = 0.f; }
  if (lane == 0) { la_[wv] = ia; lb_[wv] = ib; }   // wave aggregates
  __syncthreads();
  // compose wave aggregates of waves > wv, ascending (E = W_{wv+1} o ... o W_3)
  float ca = 1.f, cb = 0.f;
#pragma unroll
  for (int w = 0; w < 4; ++w) {
    if (w > wv) { cb = fmaf(ca, lb_[w], cb); ca *= la_[w]; }
  }
  ea = xa * ca;
  eb = fmaf(xa, cb, xb);
  __syncthreads();   // LDS safe for reuse
}

template <bool NORM>
__global__ __launch_bounds__(BLOCK)
void disc_scan(const float* __restrict__ r, long long n,
               double* __restrict__ acc, const float* __restrict__ mi,
               float* __restrict__ out) {
  __shared__ float s_la[4], s_lb[4];
  __shared__ float s_bc;
  __shared__ float s_r0[4], s_r1[4];

  const int tid = threadIdx.x;
  const long long base = (long long)blockIdx.x * CHUNK;

  // ---- lookahead: estimate carry into end of this block's chunk ----
  float cblk;
  {
    const long long la0 = base + CHUNK + (long long)tid * VPT_LA;
    float4 v0 = load4g(r, la0, n);
    float4 v1 = load4g(r, la0 + 4, n);
    float b = 0.f;
    b = fmaf(GAMMA, b, v1.w); b = fmaf(GAMMA, b, v1.z);
    b = fmaf(GAMMA, b, v1.y); b = fmaf(GAMMA, b, v1.x);
    b = fmaf(GAMMA, b, v0.w); b = fmaf(GAMMA, b, v0.z);
    b = fmaf(GAMMA, b, v0.y); b = fmaf(GAMMA, b, v0.x);
    float ea, eb;
    block_sufscan_excl(gpow(VPT_LA), b, ea, eb, s_la, s_lb);
    if (tid == 0) s_bc = fmaf(gpow(VPT_LA), eb, b);  // value at base+CHUNK (carry 0 beyond)
    __syncthreads();
    cblk = s_bc;
  }

  // ---- main segment: 32 contiguous elements per thread, held in registers ----
  const long long seg = base + (long long)tid * VPT;
  float4 buf[VPT / 4];
#pragma unroll
  for (int i = 0; i < VPT / 4; ++i) buf[i] = load4g(r, seg + 4 * i, n);

  float b = 0.f;
#pragma unroll
  for (int i = VPT / 4 - 1; i >= 0; --i) {
    b = fmaf(GAMMA, b, buf[i].w);
    b = fmaf(GAMMA, b, buf[i].z);
    b = fmaf(GAMMA, b, buf[i].y);
    b = fmaf(GAMMA, b, buf[i].x);
  }
  float ea, eb;
  block_sufscan_excl(gpow(VPT), b, ea, eb, s_la, s_lb);
  float x = fmaf(ea, cblk, eb);  // exact carry at end of this thread's segment

  if constexpr (NORM) {
    const float m = mi[0], inv = mi[1];
#pragma unroll
    for (int i = VPT / 4 - 1; i >= 0; --i) {
      x = fmaf(GAMMA, x, buf[i].w); buf[i].w = (x - m) * inv;
      x = fmaf(GAMMA, x, buf[i].z); buf[i].z = (x - m) * inv;
      x = fmaf(GAMMA, x, buf[i].y); buf[i].y = (x - m) * inv;
      x = fmaf(GAMMA, x, buf[i].x); buf[i].x = (x - m) * inv;
    }
#pragma unroll
    for (int i = 0; i < VPT / 4; ++i) store4g(out, seg + 4 * i, n, buf[i]);
  } else {
    float sm = 0.f, sq = 0.f;
#pragma unroll
    for (int i = VPT / 4 - 1; i >= 0; --i) {
      x = fmaf(GAMMA, x, buf[i].w); sm += x; sq = fmaf(x, x, sq);
      x = fmaf(GAMMA, x, buf[i].z); sm += x; sq = fmaf(x, x, sq);
      x = fmaf(GAMMA, x, buf[i].y); sm += x; sq = fmaf(x, x, sq);
      x = fmaf(GAMMA, x, buf[i].x); sm += x; sq = fmaf(x, x, sq);
    }
#pragma unroll
    for (int d = 32; d; d >>= 1) { sm += __shfl_down(sm, d); sq += __shfl_down(sq, d); }
    const int lane = tid & 63, wv = tid >> 6;
    if (lane == 0) { s_r0[wv] = sm; s_r1[wv] = sq; }
    __syncthreads();
    if (tid == 0) {
      double S = (double)s_r0[0] + (double)s_r0[1] + (double)s_r0[2] + (double)s_r0[3];
      double Q = (double)s_r1[0] + (double)s_r1[1] + (double)s_r1[2] + (double)s_r1[3];
      atomicAdd(acc, S);
      atomicAdd(acc + 1, Q);
    }
  }
}

__global__ void k_zero(double* __restrict__ acc) {
  acc[0] = 0.0;
  acc[1] = 0.0;
}

__global__ void k_finalize(const double* __restrict__ acc, long long n, float* __restrict__ mi) {
  double mean = acc[0] / (double)n;
  double var  = acc[1] / (double)n - mean * mean;
  if (var < 0.0) var = 0.0;
  mi[0] = (float)mean;
  mi[1] = (float)(1.0 / (sqrt(var) + EPSN));
}

extern "C" void kernel_launch(void* const* d_in, const int* in_sizes, int n_in,
                              void* d_out, int out_size, void* d_ws, size_t ws_size,
                              hipStream_t stream) {
  const float* r = (const float*)d_in[0];
  float* out = (float*)d_out;
  const long long n = (long long)in_sizes[0];

  double* acc = (double*)d_ws;                       // 16 B accumulators
  float*  mi  = (float*)((char*)d_ws + 16);          // mean, inv_std

  const int nblk = (int)((n + CHUNK - 1) / CHUNK);   // 4096 for T=2^25

  k_zero<<<1, 1, 0, stream>>>(acc);
  disc_scan<false><<<nblk, BLOCK, 0, stream>>>(r, n, acc, mi, out);
  k_finalize<<<1, 1, 0, stream>>>(acc, n, mi);
  disc_scan<true><<<nblk, BLOCK, 0, stream>>>(r, n, acc, mi, out);
}

// Round 2
// 173.358 us; speedup vs baseline: 1.0801x; 1.0801x over previous
//
#include <hip/hip_runtime.h>
#include <math.h>

// ret[t] = r[t] + g*ret[t+1]; out = (ret-mean)/(std+eps).
// gamma^2048 ~ 1.1e-9 -> each block seeds its carry from a 2048-elem lookahead
// it reads itself: zero inter-block communication.
// R2: coalesced global<->LDS staging; per-thread-contiguous segments read from
// padded LDS (36-word groups -> b128 reads at the 8-row data floor, 16B aligned).

#define GAMMA 0.99f
#define EPSN  1e-4

constexpr int BLOCK = 256;
constexpr int VPT   = 32;               // elements per thread (main)
constexpr int CHUNK = BLOCK * VPT;      // 8192 per block
constexpr int LA    = 2048;             // lookahead elements (gamma^2048 ~ 1e-9)
constexpr int TOT   = CHUNK + LA;       // 10240 staged per block
constexpr int GRP   = 36;               // 32 data + 4 pad words per group
constexpr int LDSW  = (TOT / 32) * GRP; // 11520 words = 45 KiB -> 3 blocks/CU

__host__ __device__ constexpr float gpow(int k) {
  double p = 1.0;
  for (int i = 0; i < k; ++i) p *= 0.99;
  return (float)p;
}

__device__ __forceinline__ int ldsw(int e) { return (e >> 5) * GRP + (e & 31); }

__device__ __forceinline__ float4 load4g(const float* __restrict__ p, long long i, long long n) {
  if (i + 3 < n) return *reinterpret_cast<const float4*>(p + i);
  float4 v = make_float4(0.f, 0.f, 0.f, 0.f);   // beyond-end == semantic zero
  if (i < n)     v.x = p[i];
  if (i + 1 < n) v.y = p[i + 1];
  if (i + 2 < n) v.z = p[i + 2];
  return v;
}

__device__ __forceinline__ void store4g(float* __restrict__ p, long long i, long long n, float4 v) {
  if (i + 3 < n) { *reinterpret_cast<float4*>(p + i) = v; return; }
  if (i < n)     p[i] = v.x;
  if (i + 1 < n) p[i + 1] = v.y;
  if (i + 2 < n) p[i + 2] = v.z;
}

// Affine f(x) = b + a*x per thread; suffix composition over threads.
__device__ __forceinline__ void wave_sufscan(float& a, float& b, int lane) {
#pragma unroll
  for (int d = 1; d < 64; d <<= 1) {
    float oa = __shfl_down(a, d);
    float ob = __shfl_down(b, d);
    if (lane + d < 64) { b = fmaf(a, ob, b); a *= oa; }
  }
}

// Exclusive suffix over the 256-thread block (composition of threads > t).
__device__ __forceinline__ void block_sufscan_excl(float a, float b, float& ea, float& eb,
                                                   float* la_, float* lb_) {
  const int lane = threadIdx.x & 63;
  const int wv   = threadIdx.x >> 6;
  float ia = a, ib = b;
  wave_sufscan(ia, ib, lane);
  float xa = __shfl_down(ia, 1);
  float xb = __shfl_down(ib, 1);
  if (lane == 63) { xa = 1.f; xb = 0.f; }
  if (lane == 0) { la_[wv] = ia; lb_[wv] = ib; }
  __syncthreads();
  float ca = 1.f, cb = 0.f;
#pragma unroll
  for (int w = 0; w < 4; ++w) {
    if (w > wv) { cb = fmaf(ca, lb_[w], cb); ca *= la_[w]; }
  }
  ea = xa * ca;
  eb = fmaf(xa, cb, xb);
  __syncthreads();
}

template <bool NORM>
__global__ __launch_bounds__(BLOCK)
void disc_scan(const float* __restrict__ r, long long n,
               double* __restrict__ acc, const float* __restrict__ mi,
               float* __restrict__ out) {
  __shared__ float lds[LDSW];
  __shared__ float s_la[4], s_lb[4];
  __shared__ float s_bc;
  __shared__ float s_r0[4], s_r1[4];

  const int tid = threadIdx.x;
  const long long base = (long long)blockIdx.x * CHUNK;

  // ---- coalesced global -> padded LDS (main chunk + lookahead, contiguous) ----
#pragma unroll
  for (int it = 0; it < TOT / 4 / BLOCK; ++it) {   // 10 float4 per thread
    const int e = 4 * (it * BLOCK + tid);
    float4 v = load4g(r, base + e, n);
    *reinterpret_cast<float4*>(&lds[ldsw(e)]) = v;
  }
  __syncthreads();

  // ---- lookahead: carry at element base+CHUNK (carry 0 beyond lookahead) ----
  float cblk;
  {
    const int e0 = CHUNK + 8 * tid;
    float4 v0 = *reinterpret_cast<const float4*>(&lds[ldsw(e0)]);
    float4 v1 = *reinterpret_cast<const float4*>(&lds[ldsw(e0 + 4)]);
    float b = 0.f;
    b = fmaf(GAMMA, b, v1.w); b = fmaf(GAMMA, b, v1.z);
    b = fmaf(GAMMA, b, v1.y); b = fmaf(GAMMA, b, v1.x);
    b = fmaf(GAMMA, b, v0.w); b = fmaf(GAMMA, b, v0.z);
    b = fmaf(GAMMA, b, v0.y); b = fmaf(GAMMA, b, v0.x);
    float ea, eb;
    block_sufscan_excl(gpow(8), b, ea, eb, s_la, s_lb);
    if (tid == 0) s_bc = fmaf(gpow(8), eb, b);
    __syncthreads();
    cblk = s_bc;
  }

  // ---- main: 32 contiguous elements per thread from padded LDS ----
  float4 buf[VPT / 4];
#pragma unroll
  for (int j = 0; j < VPT / 4; ++j)
    buf[j] = *reinterpret_cast<const float4*>(&lds[ldsw(VPT * tid + 4 * j)]);

  float b = 0.f;
#pragma unroll
  for (int i = VPT / 4 - 1; i >= 0; --i) {
    b = fmaf(GAMMA, b, buf[i].w);
    b = fmaf(GAMMA, b, buf[i].z);
    b = fmaf(GAMMA, b, buf[i].y);
    b = fmaf(GAMMA, b, buf[i].x);
  }
  float ea, eb;
  block_sufscan_excl(gpow(VPT), b, ea, eb, s_la, s_lb);
  float x = fmaf(ea, cblk, eb);   // exact carry at end of this thread's segment

  if constexpr (NORM) {
    const float m = mi[0], inv = mi[1];
#pragma unroll
    for (int i = VPT / 4 - 1; i >= 0; --i) {
      x = fmaf(GAMMA, x, buf[i].w); buf[i].w = (x - m) * inv;
      x = fmaf(GAMMA, x, buf[i].z); buf[i].z = (x - m) * inv;
      x = fmaf(GAMMA, x, buf[i].y); buf[i].y = (x - m) * inv;
      x = fmaf(GAMMA, x, buf[i].x); buf[i].x = (x - m) * inv;
    }
    // write normalized values back to this thread's OWN LDS slots (no hazard)
#pragma unroll
    for (int j = 0; j < VPT / 4; ++j)
      *reinterpret_cast<float4*>(&lds[ldsw(VPT * tid + 4 * j)]) = buf[j];
    __syncthreads();
    // coalesced LDS -> global (main region only)
#pragma unroll
    for (int it = 0; it < CHUNK / 4 / BLOCK; ++it) {  // 8 float4 per thread
      const int e = 4 * (it * BLOCK + tid);
      float4 v = *reinterpret_cast<const float4*>(&lds[ldsw(e)]);
      store4g(out, base + e, n, v);
    }
  } else {
    float sm = 0.f, sq = 0.f;
#pragma unroll
    for (int i = VPT / 4 - 1; i >= 0; --i) {
      x = fmaf(GAMMA, x, buf[i].w); sm += x; sq = fmaf(x, x, sq);
      x = fmaf(GAMMA, x, buf[i].z); sm += x; sq = fmaf(x, x, sq);
      x = fmaf(GAMMA, x, buf[i].y); sm += x; sq = fmaf(x, x, sq);
      x = fmaf(GAMMA, x, buf[i].x); sm += x; sq = fmaf(x, x, sq);
    }
#pragma unroll
    for (int d = 32; d; d >>= 1) { sm += __shfl_down(sm, d); sq += __shfl_down(sq, d); }
    const int lane = tid & 63, wv = tid >> 6;
    if (lane == 0) { s_r0[wv] = sm; s_r1[wv] = sq; }
    __syncthreads();
    if (tid == 0) {
      double S = (double)s_r0[0] + (double)s_r0[1] + (double)s_r0[2] + (double)s_r0[3];
      double Q = (double)s_r1[0] + (double)s_r1[1] + (double)s_r1[2] + (double)s_r1[3];
      atomicAdd(acc, S);
      atomicAdd(acc + 1, Q);
    }
  }
}

__global__ void k_zero(double* __restrict__ acc) {
  acc[0] = 0.0;
  acc[1] = 0.0;
}

__global__ void k_finalize(const double* __restrict__ acc, long long n, float* __restrict__ mi) {
  double mean = acc[0] / (double)n;
  double var  = acc[1] / (double)n - mean * mean;
  if (var < 0.0) var = 0.0;
  mi[0] = (float)mean;
  mi[1] = (float)(1.0 / (sqrt(var) + EPSN));
}

extern "C" void kernel_launch(void* const* d_in, const int* in_sizes, int n_in,
                              void* d_out, int out_size, void* d_ws, size_t ws_size,
                              hipStream_t stream) {
  const float* r = (const float*)d_in[0];
  float* out = (float*)d_out;
  const long long n = (long long)in_sizes[0];

  double* acc = (double*)d_ws;                 // 16 B accumulators
  float*  mi  = (float*)((char*)d_ws + 16);    // mean, inv_std

  const int nblk = (int)((n + CHUNK - 1) / CHUNK);  // 4096 for T=2^25

  k_zero<<<1, 1, 0, stream>>>(acc);
  disc_scan<false><<<nblk, BLOCK, 0, stream>>>(r, n, acc, mi, out);
  k_finalize<<<1, 1, 0, stream>>>(acc, n, mi);
  disc_scan<true><<<nblk, BLOCK, 0, stream>>>(r, n, acc, mi, out);
}

// Round 3
// 101.807 us; speedup vs baseline: 1.8393x; 1.7028x over previous
//
#include <hip/hip_runtime.h>
#include <math.h>

// ret[t] = r[t] + g*ret[t+1]; out = (ret-mean)/(std+eps).
// gamma^2048 ~ 1.1e-9 -> each block seeds its carry from a 2048-elem lookahead
// it reads itself: zero inter-block communication.
// R3: pass1 = scan + stats + write unnormalized returns (one scan total);
//     pass2 = pure streaming normalize (calibration probe for streaming rate).
// Scan latency cuts: lookahead in regs (LDS 36KB -> 4 blocks/CU), ILP-2 fused
// wave scans, 3 barriers (was 6), atomics spread over 32 slots.

#define GAMMA 0.99f
#define EPSN  1e-4

constexpr int BLOCK = 256;
constexpr int VPT   = 32;                  // main elements per thread
constexpr int CHUNK = BLOCK * VPT;         // 8192 per block
constexpr int LAPT  = 8;                   // lookahead elems/thread (2048 total)
constexpr int GRP   = 36;                  // 32 data + 4 pad words
constexpr int LDSW  = (CHUNK / 32) * GRP;  // 9216 words = 36 KiB -> 4 blocks/CU
constexpr int NACC  = 32;                  // atomic slot pairs

__host__ __device__ constexpr float gpow(int k) {
  double p = 1.0;
  for (int i = 0; i < k; ++i) p *= 0.99;
  return (float)p;
}

__device__ __forceinline__ int ldsw(int e) { return (e >> 5) * GRP + (e & 31); }

__device__ __forceinline__ float4 load4g(const float* __restrict__ p, long long i, long long n) {
  if (i + 3 < n) return *reinterpret_cast<const float4*>(p + i);
  float4 v = make_float4(0.f, 0.f, 0.f, 0.f);   // beyond-end == semantic zero
  if (i < n)     v.x = p[i];
  if (i + 1 < n) v.y = p[i + 1];
  if (i + 2 < n) v.z = p[i + 2];
  return v;
}

__device__ __forceinline__ void store4g(float* __restrict__ p, long long i, long long n, float4 v) {
  if (i + 3 < n) { *reinterpret_cast<float4*>(p + i) = v; return; }
  if (i < n)     p[i] = v.x;
  if (i + 1 < n) p[i + 1] = v.y;
  if (i + 2 < n) p[i + 2] = v.z;
}

__global__ __launch_bounds__(BLOCK)
void scan_stats(const float* __restrict__ r, long long n,
                double* __restrict__ acc, float* __restrict__ out) {
  __shared__ float lds[LDSW];
  __shared__ float wmA[4], wmB[4], wlA[4], wlB[4];
  __shared__ float r0[4], r1[4];

  const int tid  = threadIdx.x;
  const int lane = tid & 63, wv = tid >> 6;
  const long long base = (long long)blockIdx.x * CHUNK;

  // lookahead -> registers (8 contiguous floats/thread)
  const long long la0 = base + CHUNK + (long long)tid * LAPT;
  float4 l0 = load4g(r, la0, n);
  float4 l1 = load4g(r, la0 + 4, n);

  // coalesced global -> padded LDS (main chunk only)
  float4 st[8];
#pragma unroll
  for (int it = 0; it < 8; ++it) st[it] = load4g(r, base + 4 * (it * BLOCK + tid), n);
#pragma unroll
  for (int it = 0; it < 8; ++it)
    *reinterpret_cast<float4*>(&lds[ldsw(4 * (it * BLOCK + tid))]) = st[it];
  __syncthreads();                                             // barrier 1

  // per-thread contiguous segment from padded LDS
  float4 buf[8];
#pragma unroll
  for (int j = 0; j < 8; ++j)
    buf[j] = *reinterpret_cast<const float4*>(&lds[ldsw(VPT * tid + 4 * j)]);

  // per-thread affine aggregates: main (len 32) and lookahead (len 8)
  float bm = 0.f;
#pragma unroll
  for (int i = 7; i >= 0; --i) {
    bm = fmaf(GAMMA, bm, buf[i].w); bm = fmaf(GAMMA, bm, buf[i].z);
    bm = fmaf(GAMMA, bm, buf[i].y); bm = fmaf(GAMMA, bm, buf[i].x);
  }
  float bl = 0.f;
  bl = fmaf(GAMMA, bl, l1.w); bl = fmaf(GAMMA, bl, l1.z);
  bl = fmaf(GAMMA, bl, l1.y); bl = fmaf(GAMMA, bl, l1.x);
  bl = fmaf(GAMMA, bl, l0.w); bl = fmaf(GAMMA, bl, l0.z);
  bl = fmaf(GAMMA, bl, l0.y); bl = fmaf(GAMMA, bl, l0.x);

  // fused ILP-2 inclusive wave suffix scans (main + lookahead)
  float ia = gpow(VPT), ib = bm;
  float ja = gpow(LAPT), jb = bl;
#pragma unroll
  for (int d = 1; d < 64; d <<= 1) {
    float oa = __shfl_down(ia, d), ob = __shfl_down(ib, d);
    float pa = __shfl_down(ja, d), pb = __shfl_down(jb, d);
    if (lane + d < 64) {
      ib = fmaf(ia, ob, ib); ia *= oa;
      jb = fmaf(ja, pb, jb); ja *= pa;
    }
  }
  float xa = __shfl_down(ia, 1), xb = __shfl_down(ib, 1);   // wave-exclusive (main)
  if (lane == 63) { xa = 1.f; xb = 0.f; }
  if (lane == 0) { wmA[wv] = ia; wmB[wv] = ib; wlA[wv] = ja; wlB[wv] = jb; }
  __syncthreads();                                             // barrier 2

  // carry into this block's end: cblk = Wl0(Wl1(Wl2(Wl3(0))))
  float cb = 0.f;
#pragma unroll
  for (int w = 3; w >= 0; --w) cb = fmaf(wlA[w], cb, wlB[w]);
  // apply main-wave aggregates of waves > wv, then wave-exclusive map
  float cw = cb;
#pragma unroll
  for (int w = 3; w >= 1; --w)
    if (w > wv) cw = fmaf(wmA[w], cw, wmB[w]);
  float x = fmaf(xa, cw, xb);    // exact carry at end of this thread's segment

  // backward pass: produce returns + accumulate stats
  float sm = 0.f, sq = 0.f;
#pragma unroll
  for (int i = 7; i >= 0; --i) {
    x = fmaf(GAMMA, x, buf[i].w); buf[i].w = x; sm += x; sq = fmaf(x, x, sq);
    x = fmaf(GAMMA, x, buf[i].z); buf[i].z = x; sm += x; sq = fmaf(x, x, sq);
    x = fmaf(GAMMA, x, buf[i].y); buf[i].y = x; sm += x; sq = fmaf(x, x, sq);
    x = fmaf(GAMMA, x, buf[i].x); buf[i].x = x; sm += x; sq = fmaf(x, x, sq);
  }
  // write returns to own LDS slots (no hazard: per-thread ownership)
#pragma unroll
  for (int j = 0; j < 8; ++j)
    *reinterpret_cast<float4*>(&lds[ldsw(VPT * tid + 4 * j)]) = buf[j];

  // block stats reduction (ILP-2 shuffles)
#pragma unroll
  for (int d = 32; d; d >>= 1) { sm += __shfl_down(sm, d); sq += __shfl_down(sq, d); }
  if (lane == 0) { r0[wv] = sm; r1[wv] = sq; }
  __syncthreads();                                             // barrier 3

  // coalesced LDS -> global (unnormalized returns)
#pragma unroll
  for (int it = 0; it < 8; ++it) {
    const int e = 4 * (it * BLOCK + tid);
    store4g(out, base + e, n, *reinterpret_cast<const float4*>(&lds[ldsw(e)]));
  }

  if (tid == 0) {
    double S = (double)r0[0] + r0[1] + r0[2] + r0[3];
    double Q = (double)r1[0] + r1[1] + r1[2] + r1[3];
    const int slot = (blockIdx.x & (NACC - 1)) * 2;
    atomicAdd(&acc[slot], S);
    atomicAdd(&acc[slot + 1], Q);
  }
}

// pure streaming normalize: in-place on out. Zero LDS/barriers/shuffles.
__global__ void k_norm(float* __restrict__ out, long long n, const float* __restrict__ mi) {
  const float m = mi[0], inv = mi[1];
  const long long n4 = n >> 2;
  float4* p = reinterpret_cast<float4*>(out);
  long long i = (long long)blockIdx.x * blockDim.x + threadIdx.x;
  const long long stride = (long long)gridDim.x * blockDim.x;
  for (; i < n4; i += stride) {
    float4 v = p[i];
    v.x = (v.x - m) * inv; v.y = (v.y - m) * inv;
    v.z = (v.z - m) * inv; v.w = (v.w - m) * inv;
    p[i] = v;
  }
  if (blockIdx.x == 0 && threadIdx.x == 0) {          // scalar tail (n%4)
    for (long long t = n4 << 2; t < n; ++t) out[t] = (out[t] - m) * inv;
  }
}

__global__ void k_zero(double* __restrict__ acc) {
  const int t = threadIdx.x;
  if (t < 2 * NACC) acc[t] = 0.0;
}

__global__ void k_finalize(const double* __restrict__ acc, long long n, float* __restrict__ mi) {
  double S = 0.0, Q = 0.0;
  for (int i = 0; i < NACC; ++i) { S += acc[2 * i]; Q += acc[2 * i + 1]; }
  double mean = S / (double)n;
  double var  = Q / (double)n - mean * mean;
  if (var < 0.0) var = 0.0;
  mi[0] = (float)mean;
  mi[1] = (float)(1.0 / (sqrt(var) + EPSN));
}

extern "C" void kernel_launch(void* const* d_in, const int* in_sizes, int n_in,
                              void* d_out, int out_size, void* d_ws, size_t ws_size,
                              hipStream_t stream) {
  const float* r = (const float*)d_in[0];
  float* out = (float*)d_out;
  const long long n = (long long)in_sizes[0];

  double* acc = (double*)d_ws;                     // 64 doubles = 512 B
  float*  mi  = (float*)((char*)d_ws + 512);       // mean, inv_std

  const int nblk = (int)((n + CHUNK - 1) / CHUNK); // 4096 for T=2^25

  k_zero<<<1, 64, 0, stream>>>(acc);
  scan_stats<<<nblk, BLOCK, 0, stream>>>(r, n, acc, out);
  k_finalize<<<1, 1, 0, stream>>>(acc, n, mi);
  k_norm<<<2048, BLOCK, 0, stream>>>(out, n, mi);
}